// Round 7
// baseline (207.722 us; speedup 1.0000x reference)
//
#include <hip/hip_runtime.h>

#define NGRAPH 256
#define NN     128   // nodes per graph
#define NT     16    // templates
#define NM     10    // template nodes
#define OUTER_IT 5
#define SINK_IT  20

// K = exp(-20*tens) = exp2(-20*log2(e)*tens)
#define SC1  28.85390081777927f    // 20*log2(e)
#define SC2  57.70780163555854f    // 40*log2(e)

typedef unsigned long long u64;
typedef float v2f __attribute__((ext_vector_type(2)));
typedef float v4f __attribute__((ext_vector_type(4)));
typedef _Float16 h2 __attribute__((ext_vector_type(2)));

static __device__ __forceinline__ v2f pkfma(v2f a, v2f b, v2f c) {
  return __builtin_elementwise_fma(a, b, c);
}
static __device__ __forceinline__ v2f bc2(float s) { return (v2f){s, s}; }
static __device__ __forceinline__ h2 u2h(unsigned u) { h2 r; __builtin_memcpy(&r, &u, 4); return r; }
// pack two fp32 -> f16x2 (round-toward-zero); bit-cast native __fp16x2 result
static __device__ __forceinline__ unsigned pkrtz(float x, float y) {
  auto h = __builtin_amdgcn_cvt_pkrtz(x, y);
  unsigned r; __builtin_memcpy(&r, &h, 4); return r;
}

// DPP xor-butterfly add within a 16-lane row (masks {1,2,7,15} span (Z2)^4).
template <int CTRL>
__device__ __forceinline__ float dpp_add(float a) {
  int t = __builtin_amdgcn_update_dpp(0, __float_as_int(a), CTRL, 0xf, 0xf, true);
  return a + __int_as_float(t);
}
// Sum over each 32-lane group; result broadcast to all lanes of the group.
__device__ __forceinline__ float allsum32(float x) {
  x = dpp_add<0xB1>(x);    // quad_perm xor 1
  x = dpp_add<0x4E>(x);    // quad_perm xor 2
  x = dpp_add<0x141>(x);   // row_half_mirror: xor 7
  x = dpp_add<0x140>(x);   // row_mirror: xor 15
  int sw = __builtin_amdgcn_ds_swizzle(__float_as_int(x), 0x401F); // xor 16
  return x + __int_as_float(sw);
}

// 32 lanes per (graph b, template t) pair, 2 pairs per 64-thread single-wave
// block. Lane owns 4 rows r = sub + 32*c. Adjacency: LDS bitmask (shared).
// P: LDS as f16x2-packed rows (5 u32 payload, stride 6 u32 = 24 B so b64/b32
// reads stay aligned and row starts spread over 16 banks). fp32 math packed
// 2-wide over the 10-column axis (v_pk_fma_f32); gather accumulates in
// v_pk_add_f16.
__global__ __launch_bounds__(64, 2)
void tgw_kernel(const int* __restrict__ ei,
                const float* __restrict__ tadj,
                const float* __restrict__ q0g,
                float* __restrict__ out,
                int E, int ne) {
  const int lane = threadIdx.x;
  const int p    = lane >> 5;        // pair slot 0/1
  const int sub  = lane & 31;
  const int b    = blockIdx.x >> 3;
  const int t0   = (blockIdx.x & 7) * 2;   // templates t0, t0+1

  __shared__ __align__(16) unsigned adj[NN][4];    // 2 KB
  __shared__ __align__(16) unsigned Pf[2][NN][6];  // 6 KB, f16x2 P rows
  __shared__ __align__(16) v2f C2T[2][NM][6];      // SC2*C2, [m][jpair], row 48B
  __shared__ float q0s[2][NM];

  // ---- stage ----
  for (int i = lane; i < NN * 4; i += 64) (&adj[0][0])[i] = 0u;
  // C2T[tt][m][jp] = SC2 * { C2[2jp][m], C2[2jp+1][m] }  (transposed pairs)
  for (int i = lane; i < 2 * NM * 5; i += 64) {
    int tt = i / 50, r = i % 50, m = r / 5, jp = r % 5;
    const float* bp = tadj + (t0 + tt) * NM * NM + m;
    C2T[tt][m][jp] = (v2f){bp[(2 * jp) * NM], bp[(2 * jp + 1) * NM]} * SC2;
  }
  if (lane < 2 * NM) q0s[lane / NM][lane % NM] = q0g[t0 * NM + lane];
  __syncthreads();

  // symmetric 0/1 adjacency from the edge list (dups/self-loops harmless)
  const int* srcp = ei;
  const int* dstp = ei + E;
  const int ebase = b * ne;
  for (int e = lane; e < ne; e += 64) {
    int s = srcp[ebase + e] & (NN - 1);
    int d = dstp[ebase + e] & (NN - 1);
    atomicOr(&adj[s][d >> 5], 1u << (d & 31));
    atomicOr(&adj[d][s >> 5], 1u << (s & 31));
  }
  __syncthreads();

  // ---- per-pair constants ----
  float qv[NM];
  {
    float mx = q0s[p][0];
    #pragma unroll
    for (int j = 1; j < NM; ++j) mx = fmaxf(mx, q0s[p][j]);
    float s = 0.f;
    #pragma unroll
    for (int j = 0; j < NM; ++j) { qv[j] = __expf(q0s[p][j] - mx); s += qv[j]; }
    float inv = __builtin_amdgcn_rcpf(s);
    #pragma unroll
    for (int j = 0; j < NM; ++j) qv[j] *= inv;
  }
  v2f q2[5];
  #pragma unroll
  for (int jp = 0; jp < 5; ++jp) q2[jp] = (v2f){qv[2 * jp], qv[2 * jp + 1]};

  // fq2[jp] = -SC1 * f2q[jpair]; qC2T[jp] = sum_m q[m]*C2T[m][jp]
  v2f fq2[5], qC2T[5];
  {
    #pragma unroll
    for (int jp = 0; jp < 5; ++jp) { fq2[jp] = (v2f){0.f, 0.f}; qC2T[jp] = (v2f){0.f, 0.f}; }
    #pragma unroll
    for (int m = 0; m < NM; ++m) {
      v2f qb = bc2(qv[m]);
      #pragma unroll
      for (int jp = 0; jp < 5; ++jp) {
        v2f c = C2T[p][m][jp];
        fq2[jp]  = pkfma(c * c, qb, fq2[jp]);
        qC2T[jp] = pkfma(c, qb, qC2T[jp]);
      }
    }
    const float f = -1.0f / (4.0f * SC1);   // -SC1/SC2^2
    #pragma unroll
    for (int jp = 0; jp < 5; ++jp) fq2[jp] *= f;
  }

  const float pw = 1.0f / 128.0f;
  float f1p[4], m1f1[4];
  #pragma unroll
  for (int c = 0; c < 4; ++c) {
    uint4 mm = *(const uint4*)&adj[sub + 32 * c][0];
    u64 m0 = mm.x | ((u64)mm.y << 32), m1 = mm.z | ((u64)mm.w << 32);
    f1p[c]  = (float)(__popcll(m0) + __popcll(m1)) * pw;   // C1*C1 == C1
    m1f1[c] = -SC1 * f1p[c];
  }

  const unsigned* Pbase = &Pf[p][0][0];
  // sparse gather S = (C1 @ P)[row r]; f16x2 accumulate, 2-deep pipeline
  auto gatherRow = [&](int r, v2f* S2) {
    uint4 mm = *(const uint4*)&adj[r][0];
    u64 m0 = mm.x | ((u64)mm.y << 32), m1 = mm.z | ((u64)mm.w << 32);
    h2 S[5] = {};
    #pragma unroll
    for (int half = 0; half < 2; ++half) {
      u64 m = half ? m1 : m0;
      const int kb = half ? 64 : 0;
      while (m) {
        int k1 = kb + (int)__builtin_ctzll(m); m &= m - 1;
        const unsigned* r1 = Pbase + k1 * 6;
        uint2 a1 = *(const uint2*)r1;
        uint2 b1 = *(const uint2*)(r1 + 2);
        unsigned c1 = r1[4];
        if (m) {
          int k2 = kb + (int)__builtin_ctzll(m); m &= m - 1;
          const unsigned* r2 = Pbase + k2 * 6;
          uint2 a2 = *(const uint2*)r2;
          uint2 b2 = *(const uint2*)(r2 + 2);
          unsigned c2 = r2[4];
          S[0] += u2h(a1.x); S[1] += u2h(a1.y); S[2] += u2h(b1.x);
          S[3] += u2h(b1.y); S[4] += u2h(c1);
          S[0] += u2h(a2.x); S[1] += u2h(a2.y); S[2] += u2h(b2.x);
          S[3] += u2h(b2.y); S[4] += u2h(c2);
        } else {
          S[0] += u2h(a1.x); S[1] += u2h(a1.y); S[2] += u2h(b1.x);
          S[3] += u2h(b1.y); S[4] += u2h(c1);
        }
      }
    }
    #pragma unroll
    for (int h = 0; h < 5; ++h) S2[h] = (v2f){(float)S[h].x, (float)S[h].y};
  };

  // arg2[c][jp] = -SC1*tens (packed over jpairs), from S2 per row
  auto costFromS = [&](v2f Sm[4][5], v2f arg2[4][5]) {
    #pragma unroll
    for (int c = 0; c < 4; ++c)
      #pragma unroll
      for (int jp = 0; jp < 5; ++jp) arg2[c][jp] = fq2[jp] + bc2(m1f1[c]);
    #pragma unroll
    for (int m = 0; m < NM; ++m) {
      v4f X = *(const v4f*)&C2T[p][m][0];   // jp 0,1
      v4f Y = *(const v4f*)&C2T[p][m][2];   // jp 2,3
      v2f Z = *(const v2f*)&C2T[p][m][4];   // jp 4
      #pragma unroll
      for (int c = 0; c < 4; ++c) {
        float sv = (m & 1) ? Sm[c][m >> 1].y : Sm[c][m >> 1].x;
        v2f sb = bc2(sv);
        arg2[c][0] = pkfma(sb, X.xy, arg2[c][0]);
        arg2[c][1] = pkfma(sb, X.zw, arg2[c][1]);
        arg2[c][2] = pkfma(sb, Y.xy, arg2[c][2]);
        arg2[c][3] = pkfma(sb, Y.zw, arg2[c][3]);
        arg2[c][4] = pkfma(sb, Z,    arg2[c][4]);
      }
    }
  };

  v2f K2[4][5], v2[5], arg2[4][5];
  float uu[4];

  for (int o = 0; o < OUTER_IT; ++o) {
    // ---- cost -> arg2 -> K = exp2(arg) ----
    if (o == 0) {
      // P0 = p q^T => S[c][m] = f1p[c]*q[m] => sum_m S C2T = f1p[c]*qC2T
      #pragma unroll
      for (int c = 0; c < 4; ++c) {
        v2f fb = bc2(f1p[c]);
        v2f ob = bc2(m1f1[c]);
        #pragma unroll
        for (int jp = 0; jp < 5; ++jp)
          arg2[c][jp] = pkfma(fb, qC2T[jp], fq2[jp] + ob);
      }
    } else {
      v2f Sm[4][5];
      #pragma unroll
      for (int c = 0; c < 4; ++c) gatherRow(sub + 32 * c, Sm[c]);
      costFromS(Sm, arg2);
    }
    #pragma unroll
    for (int c = 0; c < 4; ++c)
      #pragma unroll
      for (int jp = 0; jp < 5; ++jp)
        K2[c][jp] = (v2f){exp2f(arg2[c][jp].x), exp2f(arg2[c][jp].y)};

    // ---- Sinkhorn (v starts at ones) ----
    #pragma unroll
    for (int jp = 0; jp < 5; ++jp) v2[jp] = (v2f){1.f, 1.f};
    for (int it = 0; it < SINK_IT; ++it) {
      #pragma unroll
      for (int c = 0; c < 4; ++c) {
        v2f d2 = K2[c][0] * v2[0];
        d2 = pkfma(K2[c][1], v2[1], d2);
        d2 = pkfma(K2[c][2], v2[2], d2);
        d2 = pkfma(K2[c][3], v2[3], d2);
        d2 = pkfma(K2[c][4], v2[4], d2);
        uu[c] = pw * __builtin_amdgcn_rcpf(d2.x + d2.y);
      }
      #pragma unroll
      for (int jp = 0; jp < 5; ++jp) {
        v2f w2 = K2[0][jp] * bc2(uu[0]);
        w2 = pkfma(K2[1][jp], bc2(uu[1]), w2);
        w2 = pkfma(K2[2][jp], bc2(uu[2]), w2);
        w2 = pkfma(K2[3][jp], bc2(uu[3]), w2);
        float cx = allsum32(w2.x);
        float cy = allsum32(w2.y);
        v2[jp] = (v2f){q2[jp].x * __builtin_amdgcn_rcpf(cx),
                       q2[jp].y * __builtin_amdgcn_rcpf(cy)};
      }
    }

    // ---- P = diag(u) K diag(v) -> LDS (f16x2 packed) ----
    __syncthreads();   // single-wave block: drains outstanding LDS ops
    #pragma unroll
    for (int c = 0; c < 4; ++c) {
      v2f ub = bc2(uu[c]);
      v2f x0 = K2[c][0] * ub * v2[0];
      v2f x1 = K2[c][1] * ub * v2[1];
      v2f x2 = K2[c][2] * ub * v2[2];
      v2f x3 = K2[c][3] * ub * v2[3];
      v2f x4 = K2[c][4] * ub * v2[4];
      unsigned* row = &Pf[p][sub + 32 * c][0];
      uint2 w01 = {pkrtz(x0.x, x0.y), pkrtz(x1.x, x1.y)};
      uint2 w23 = {pkrtz(x2.x, x2.y), pkrtz(x3.x, x3.y)};
      *(uint2*)row       = w01;
      *(uint2*)(row + 2) = w23;
      row[4]             = pkrtz(x4.x, x4.y);
    }
    __syncthreads();
  }

  // ---- GW = sum_ij tens(P)_ij * P_ij,  tens = arg * (-1/SC1) ----
  float acc = 0.f;
  {
    v2f Sm[4][5];
    #pragma unroll
    for (int c = 0; c < 4; ++c) gatherRow(sub + 32 * c, Sm[c]);
    costFromS(Sm, arg2);
    const v2f nf = bc2(-1.0f / SC1);
    v2f acc2 = (v2f){0.f, 0.f};
    #pragma unroll
    for (int c = 0; c < 4; ++c) {
      v2f ub = bc2(uu[c]);
      #pragma unroll
      for (int jp = 0; jp < 5; ++jp) {
        v2f Pv = K2[c][jp] * ub * v2[jp];
        acc2 = pkfma(arg2[c][jp] * nf, Pv, acc2);
      }
    }
    acc = acc2.x + acc2.y;
  }
  float total = allsum32(acc);
  if (sub == 0) out[b * NT + t0 + p] = total;
}

extern "C" void kernel_launch(void* const* d_in, const int* in_sizes, int n_in,
                              void* d_out, int out_size, void* d_ws, size_t ws_size,
                              hipStream_t stream) {
  // inputs: 0 x(f32, unused) 1 edge_index(int32) 2 batch(int32, unused)
  //         3 tplt_adjacencies(f32) 4 tplt_features(f32, unused) 5 q0(f32)
  const int* ei   = (const int*)d_in[1];
  const float* c2 = (const float*)d_in[3];
  const float* q0 = (const float*)d_in[5];
  float* out      = (float*)d_out;
  const int E  = in_sizes[1] / 2;
  const int ne = E / NGRAPH;
  tgw_kernel<<<dim3(NGRAPH * 8), dim3(64), 0, stream>>>(ei, c2, q0, out, E, ne);
}